// Round 8
// baseline (342.007 us; speedup 1.0000x reference)
//
#include <hip/hip_runtime.h>
#include <hip/hip_bf16.h>
#include <math.h>

// FAGCN: N=50000, E=800000, H=128, OUT=16, L=2
// Round 6 -> 7: scattered global atomics (19G/s transaction ceiling, 85us)
// replaced by atomic-free CSR build: range x slice LDS histograms (k_hist),
// slice-fold (k_red2), LDS-cursor fill (k_fill2). No global atomics, no memset.

#define EPS_RES 0.3f
constexpr int HD = 128;
constexpr int OD = 16;
constexpr int RS  = 12544;   // nodes per range (49*256) -> 50176B LDS histogram
constexpr int NSL = 32;      // edge slices

typedef __attribute__((ext_vector_type(8))) short short8v;   // 8 x bf16
typedef __attribute__((ext_vector_type(4))) float f32x4;

__device__ __forceinline__ unsigned short f2bf(float f) {    // RNE f32->bf16
    unsigned u = __builtin_bit_cast(unsigned, f);
    u += 0x7fffu + ((u >> 16) & 1u);
    return (unsigned short)(u >> 16);
}
__device__ __forceinline__ float bf2f(unsigned s) {
    return __builtin_bit_cast(float, s << 16);
}

// ---- per-(range,slice) LDS histogram of keys -> table[bid][RS], no atomics ----
__global__ __launch_bounds__(256) void k_hist(const int* __restrict__ keys, int E,
                                              int* __restrict__ table) {
    __shared__ int hl[RS];
    int r = blockIdx.x / NSL, s = blockIdx.x % NSL;
    int base = r * RS;
    for (int j = threadIdx.x; j < RS; j += 256) hl[j] = 0;
    __syncthreads();
    int ES = (E + NSL - 1) / NSL;
    int lo = s * ES, hi = min(E, lo + ES);
    for (int i = lo + threadIdx.x; i < hi; i += 256) {
        int k = keys[i] - base;
        if ((unsigned)k < (unsigned)RS) atomicAdd(&hl[k], 1);
    }
    __syncthreads();
    int* t = table + (size_t)blockIdx.x * RS;
    for (int j = threadIdx.x; j < RS; j += 256) t[j] = hl[j];
}

// ---- fold slices: dn from deg table; in-place exclusive slice-prefix of cnt
// table; per-node total cnt; per-block partial sums for the scan ----
__global__ __launch_bounds__(256) void k_red2(const int* __restrict__ deg_t,
                                              int* __restrict__ cnt_t,
                                              float* __restrict__ dn, int* __restrict__ cnt,
                                              int* __restrict__ bsum, int N) {
    int t = threadIdx.x, i = blockIdx.x * 256 + t;
    int total = 0;
    if (i < N) {
        int r = i / RS, ri = i - r * RS;
        size_t tbase = ((size_t)r * NSL) * RS + ri;
        int deg = 0;
        #pragma unroll
        for (int s = 0; s < NSL; ++s) deg += deg_t[tbase + (size_t)s * RS];
        dn[i] = rsqrtf((float)(deg < 1 ? 1 : deg));
        int run = 0;
        #pragma unroll
        for (int s = 0; s < NSL; ++s) {
            size_t idx = tbase + (size_t)s * RS;
            int c = cnt_t[idx];
            cnt_t[idx] = run;
            run += c;
        }
        total = run;
        cnt[i] = total;
    }
    __shared__ int sh[256];
    sh[t] = total;
    __syncthreads();
    #pragma unroll
    for (int d = 128; d; d >>= 1) {
        if (t < d) sh[t] += sh[t + d];
        __syncthreads();
    }
    if (t == 0) bsum[blockIdx.x] = sh[0];
}

__global__ __launch_bounds__(256) void k_scan2(int* __restrict__ bsum, int nb,
                                               int* __restrict__ rowptr, int N, int E) {
    __shared__ int s[256];
    int t = threadIdx.x;
    int v = (t < nb) ? bsum[t] : 0;
    s[t] = v;
    __syncthreads();
    #pragma unroll
    for (int d = 1; d < 256; d <<= 1) {
        int x = (t >= d) ? s[t - d] : 0;
        __syncthreads();
        s[t] += x;
        __syncthreads();
    }
    if (t < nb) bsum[t] = s[t] - v;
    if (t == 0) rowptr[N] = E;
}

__global__ __launch_bounds__(256) void k_scan3(const int* __restrict__ cnt,
                                               const int* __restrict__ bsum,
                                               int* __restrict__ rowptr, int N) {
    __shared__ int s[256];
    int t = threadIdx.x, i = blockIdx.x * 256 + t;
    int v = (i < N) ? cnt[i] : 0;
    s[t] = v;
    __syncthreads();
    #pragma unroll
    for (int d = 1; d < 256; d <<= 1) {
        int x = (t >= d) ? s[t - d] : 0;
        __syncthreads();
        s[t] += x;
        __syncthreads();
    }
    if (i < N) rowptr[i] = bsum[blockIdx.x] + s[t] - v;
}

// ---- fill CSR with LDS cursors (base = slice-prefix + rowptr) ----
__global__ __launch_bounds__(256) void k_fill2(const int* __restrict__ row,
                                               const int* __restrict__ col,
                                               const int* __restrict__ cnt_t,
                                               const int* __restrict__ rowptr,
                                               int* __restrict__ erow, int E, int N) {
    __shared__ int cur[RS];
    int r = blockIdx.x / NSL, s = blockIdx.x % NSL;
    int base = r * RS;
    const int* t = cnt_t + (size_t)blockIdx.x * RS;
    for (int j = threadIdx.x; j < RS; j += 256) {
        int node = base + j;
        cur[j] = (node < N) ? (t[j] + rowptr[node]) : 0;
    }
    __syncthreads();
    int ES = (E + NSL - 1) / NSL;
    int lo = s * ES, hi = min(E, lo + ES);
    for (int i = lo + threadIdx.x; i < hi; i += 256) {
        int c = col[i] - base;
        if ((unsigned)c < (unsigned)RS) {
            int p = atomicAdd(&cur[c], 1);
            erow[p] = row[i];
        }
    }
}

// ---- W_in -> B-fragment-packed bf16 ----
__global__ void k_wprep(const float* __restrict__ W, unsigned short* __restrict__ Wb) {
    int tid = blockIdx.x * 256 + threadIdx.x;          // 2048 threads
    int c = tid >> 8, ks = (tid >> 6) & 3, l = tid & 63;
    int colw  = c * 16 + (l & 15);
    int kbase = ks * 32 + (l >> 4) * 8;
    unsigned short tmp[8];
    #pragma unroll
    for (int j = 0; j < 8; ++j) tmp[j] = f2bf(W[(kbase + j) * HD + colw]);
    #pragma unroll
    for (int j = 0; j < 8; ++j) Wb[tid * 8 + j] = tmp[j];
}

// ---- hb0 = bf16(relu(x @ W_in + b_in)) via MFMA + fused layer-0 gate proj ----
__global__ __launch_bounds__(256) void k_gemm_mfma(
        const float* __restrict__ x, const unsigned short* __restrict__ Wb,
        const float* __restrict__ bias,
        const float* __restrict__ Wg0, const float* __restrict__ bg,
        const float* __restrict__ dn,
        unsigned short* __restrict__ hb,
        float2* __restrict__ adn, float* __restrict__ bplus, int N) {
    int wid  = blockIdx.x * 4 + (threadIdx.x >> 6);
    int lane = threadIdx.x & 63;
    int r0 = wid * 16;
    int lr = lane & 15, lg = lane >> 4;
    int rload = r0 + lr; if (rload > N - 1) rload = N - 1;
    f32x4 acc[8];
    #pragma unroll
    for (int c = 0; c < 8; ++c) acc[c] = (f32x4){0.f, 0.f, 0.f, 0.f};
    #pragma unroll
    for (int ks = 0; ks < 4; ++ks) {
        const float4* xr = (const float4*)(x + (size_t)rload * HD + ks * 32 + lg * 8);
        float4 f0 = xr[0], f1 = xr[1];
        short8v a;
        a[0] = (short)f2bf(f0.x); a[1] = (short)f2bf(f0.y);
        a[2] = (short)f2bf(f0.z); a[3] = (short)f2bf(f0.w);
        a[4] = (short)f2bf(f1.x); a[5] = (short)f2bf(f1.y);
        a[6] = (short)f2bf(f1.z); a[7] = (short)f2bf(f1.w);
        #pragma unroll
        for (int c = 0; c < 8; ++c) {
            short8v b = *(const short8v*)(Wb + ((c * 4 + ks) * 64 + lane) * 8);
            acc[c] = __builtin_amdgcn_mfma_f32_16x16x32_bf16(a, b, acc[c], 0, 0, 0);
        }
    }
    float pa[4] = {0.f, 0.f, 0.f, 0.f}, pb[4] = {0.f, 0.f, 0.f, 0.f};
    #pragma unroll
    for (int c = 0; c < 8; ++c) {
        int colw = c * 16 + lr;
        float bv = bias[colw];
        float w1 = Wg0[colw], w2 = Wg0[HD + colw];
        #pragma unroll
        for (int i = 0; i < 4; ++i) {
            int r = r0 + lg * 4 + i;
            float v = acc[c][i] + bv;
            v = v > 0.0f ? v : 0.0f;
            if (r < N) hb[(size_t)r * HD + colw] = f2bf(v);
            pa[i] += v * w1;
            pb[i] += v * w2;
        }
    }
    #pragma unroll
    for (int mask = 1; mask <= 8; mask <<= 1) {
        #pragma unroll
        for (int i = 0; i < 4; ++i) {
            pa[i] += __shfl_xor(pa[i], mask);
            pb[i] += __shfl_xor(pb[i], mask);
        }
    }
    if (lr == 0) {
        float bg0 = bg[0];
        #pragma unroll
        for (int i = 0; i < 4; ++i) {
            int r = r0 + lg * 4 + i;
            if (r < N) {
                adn[r]   = make_float2(pa[i], dn[r]);
                bplus[r] = pb[i] + bg0;
            }
        }
    }
}

// ---- aggregate + residual(bf16 hb0) + fused next-layer gate projections ----
__global__ __launch_bounds__(256) void k_agg(
        const int* __restrict__ rowptr, const int* __restrict__ erow,
        const float2* __restrict__ adn, const float* __restrict__ bplus,
        const float* __restrict__ dn,
        const unsigned short* __restrict__ hb_in, const unsigned short* __restrict__ hb0,
        unsigned short* __restrict__ hb_out,
        const float* __restrict__ wg_next, const float* __restrict__ bg, int next_layer,
        float2* __restrict__ adn_out, float* __restrict__ bplus_out, int N) {
    int v = (int)((blockIdx.x * (size_t)blockDim.x + threadIdx.x) >> 6);
    if (v >= N) return;
    int lane = threadIdx.x & 63;
    int hl = lane & 31, half = lane >> 5;
    int beg = rowptr[v], end = rowptr[v + 1];
    float bv = bplus[v];
    float ax = 0.f, ay = 0.f, az = 0.f, aw = 0.f;
    for (int s0 = beg; s0 < end; s0 += 64) {
        int m = end - s0; if (m > 64) m = 64;
        int r_l = 0; float nrm_l = 0.0f;
        if (lane < m) {
            r_l = erow[s0 + lane];
            float2 ad = adn[r_l];
            nrm_l = tanhf(ad.x + bv) * ad.y;     // dn[v] factored out
        }
        int it = (m + 1) >> 1;
        for (int j = 0; j < it; ++j) {
            int src = 2 * j + half;
            int   r  = __shfl(r_l, src);
            float nv = __shfl(nrm_l, src);
            if (src < m) {
                uint2 u = *(const uint2*)(hb_in + (size_t)r * HD + hl * 4);
                ax += nv * bf2f(u.x & 0xffffu);
                ay += nv * bf2f(u.x >> 16);
                az += nv * bf2f(u.y & 0xffffu);
                aw += nv * bf2f(u.y >> 16);
            }
        }
    }
    ax += __shfl_xor(ax, 32);
    ay += __shfl_xor(ay, 32);
    az += __shfl_xor(az, 32);
    aw += __shfl_xor(aw, 32);
    float dnv = dn[v];
    uint2 u0 = *(const uint2*)(hb0 + (size_t)v * HD + hl * 4);
    float o0 = EPS_RES * bf2f(u0.x & 0xffffu) + dnv * ax;
    float o1 = EPS_RES * bf2f(u0.x >> 16)     + dnv * ay;
    float o2 = EPS_RES * bf2f(u0.y & 0xffffu) + dnv * az;
    float o3 = EPS_RES * bf2f(u0.y >> 16)     + dnv * aw;
    if (half == 0) {
        uint2 up;
        up.x = (unsigned)f2bf(o0) | ((unsigned)f2bf(o1) << 16);
        up.y = (unsigned)f2bf(o2) | ((unsigned)f2bf(o3) << 16);
        *(uint2*)(hb_out + (size_t)v * HD + hl * 4) = up;
    }
    if (wg_next != nullptr) {
        float4 w1 = *(const float4*)(wg_next + hl * 4);
        float4 w2 = *(const float4*)(wg_next + HD + hl * 4);
        float pa = o0 * w1.x + o1 * w1.y + o2 * w1.z + o3 * w1.w;
        float pb = o0 * w2.x + o1 * w2.y + o2 * w2.z + o3 * w2.w;
        #pragma unroll
        for (int m = 16; m; m >>= 1) {
            pa += __shfl_xor(pa, m);
            pb += __shfl_xor(pb, m);
        }
        if (lane == 0) {
            adn_out[v]   = make_float2(pa, dnv);
            bplus_out[v] = pb + bg[next_layer];
        }
    }
}

// ---- out = log_softmax(h @ W_out + b_out); 16 threads/node, bf16 h ----
__global__ __launch_bounds__(256) void k_out(
        const unsigned short* __restrict__ hb, const float* __restrict__ W,
        const float* __restrict__ bias, float* __restrict__ out, int N) {
    __shared__ float Ws[HD * OD];
    __shared__ unsigned hsu[16 * 64];
    int t = threadIdx.x;
    for (int i = t; i < HD * OD; i += 256) Ws[i] = W[i];
    int n0 = blockIdx.x * 16;
    for (int i = t; i < 16 * 64; i += 256) {
        int node = n0 + (i >> 6);
        hsu[i] = (node < N) ? *(const unsigned*)(hb + (size_t)node * HD + (i & 63) * 2) : 0u;
    }
    __syncthreads();
    int n = n0 + (t >> 4);
    int j = t & 15;
    if (n < N) {
        const unsigned* hrow = &hsu[(t >> 4) * 64];
        float acc = bias[j];
        #pragma unroll 8
        for (int p = 0; p < 64; ++p) {
            unsigned u = hrow[p];
            acc += bf2f(u & 0xffffu) * Ws[(2 * p) * OD + j]
                 + bf2f(u >> 16)     * Ws[(2 * p + 1) * OD + j];
        }
        float m = acc;
        #pragma unroll
        for (int msk = 8; msk; msk >>= 1) m = fmaxf(m, __shfl_xor(m, msk, 16));
        float ex = expf(acc - m);
        float s = ex;
        #pragma unroll
        for (int msk = 8; msk; msk >>= 1) s += __shfl_xor(s, msk, 16);
        out[n * OD + j] = acc - m - logf(s);
    }
}

extern "C" void kernel_launch(void* const* d_in, const int* in_sizes, int n_in,
                              void* d_out, int out_size, void* d_ws, size_t ws_size,
                              hipStream_t stream) {
    const float* x     = (const float*)d_in[0];
    const int*   ei    = (const int*)  d_in[1];
    const float* W_in  = (const float*)d_in[2];
    const float* b_in  = (const float*)d_in[3];
    const float* Wg    = (const float*)d_in[4];
    const float* bg    = (const float*)d_in[5];
    const float* W_out = (const float*)d_in[6];
    const float* b_out = (const float*)d_in[7];
    float* out = (float*)d_out;

    const int N = in_sizes[0] / HD;
    const int E = in_sizes[1] / 2;
    const int L = in_sizes[5];
    const int* row = ei;
    const int* col = ei + E;

    const int tiles   = (N + 15) / 16;
    const int gblocks = (tiles + 3) / 4;
    const int nb      = (N + 255) / 256;          // 196 <= 256
    const int R       = (N + RS - 1) / RS;        // 4 ranges

    // ---- workspace bump allocator (256B aligned) ----
    char* ws = (char*)d_ws;
    size_t off = 0;
    auto alloc = [&](size_t bytes) -> void* {
        void* p = ws + off;
        off = (off + bytes + 255) & ~(size_t)255;
        return p;
    };
    int*            deg_t  = (int*)           alloc((size_t)R * NSL * RS * 4);  // 6.4MB
    int*            cnt_t  = (int*)           alloc((size_t)R * NSL * RS * 4);  // 6.4MB
    float*          dn     = (float*)         alloc((size_t)N * 4);
    int*            cnt    = (int*)           alloc((size_t)N * 4);
    float2*         adnA   = (float2*)        alloc((size_t)N * 8);
    float2*         adnB   = (float2*)        alloc((size_t)N * 8);
    float*          bplusA = (float*)         alloc((size_t)N * 4);
    float*          bplusB = (float*)         alloc((size_t)N * 4);
    int*            bsum   = (int*)           alloc((size_t)nb * 4);
    int*            rowptr = (int*)           alloc(((size_t)N + 1) * 4);
    int*            erow   = (int*)           alloc((size_t)E * 4);
    unsigned short* Wb     = (unsigned short*)alloc((size_t)HD * HD * 2);
    unsigned short* hb0    = (unsigned short*)alloc((size_t)N * HD * 2);
    unsigned short* hb1    = (unsigned short*)alloc((size_t)N * HD * 2);
    unsigned short* hb2    = (unsigned short*)alloc((size_t)N * HD * 2);
    (void)ws_size;

    // CSR build, atomic-free (no memsets needed: everything fully written)
    k_hist <<<R * NSL, 256, 0, stream>>>(row, E, deg_t);
    k_hist <<<R * NSL, 256, 0, stream>>>(col, E, cnt_t);
    k_red2 <<<nb, 256, 0, stream>>>(deg_t, cnt_t, dn, cnt, bsum, N);
    k_scan2<<<1, 256, 0, stream>>>(bsum, nb, rowptr, N, E);
    k_scan3<<<nb, 256, 0, stream>>>(cnt, bsum, rowptr, N);
    k_fill2<<<R * NSL, 256, 0, stream>>>(row, col, cnt_t, rowptr, erow, E, N);

    k_wprep<<<8, 256, 0, stream>>>(W_in, Wb);
    k_gemm_mfma<<<gblocks, 256, 0, stream>>>(x, Wb, b_in, Wg, bg, dn,
                                             hb0, adnA, bplusA, N);

    unsigned short* hcur = hb0;
    unsigned short* houts[2] = { hb1, hb2 };
    float2* adns[2]  = { adnA, adnB };
    float*  bpls[2]  = { bplusA, bplusB };
    for (int i = 0; i < L; ++i) {
        const float* wg_next = (i + 1 < L) ? (Wg + (i + 1) * 2 * HD) : nullptr;
        k_agg<<<(N + 3) / 4, 256, 0, stream>>>(
            rowptr, erow, adns[i & 1], bpls[i & 1], dn,
            hcur, hb0, houts[i & 1],
            wg_next, bg, i + 1, adns[(i + 1) & 1], bpls[(i + 1) & 1], N);
        hcur = houts[i & 1];
    }

    k_out<<<(N + 15) / 16, 256, 0, stream>>>(hcur, W_out, b_out, out, N);
}

// Round 11
// 322.542 us; speedup vs baseline: 1.0604x; 1.0604x over previous
//
#include <hip/hip_runtime.h>
#include <hip/hip_bf16.h>
#include <math.h>

// FAGCN: N=50000, E=800000, H=128, OUT=16, L=2
// Round 8 -> 9: (1) XCD-swizzled range decode (r=bid&3) so each erow range is
// written by only 2 XCDs' L2s -> partial-line merge (k_fill2 was 70us, 26MB
// writes = 32B/scattered-4B-write); (2) single fused u16-packed histogram pass;
// (3) k_agg quarter-wave: 4 edges in flight, uint4 gathers.

#define EPS_RES 0.3f
constexpr int HD = 128;
constexpr int OD = 16;
constexpr int RS  = 12544;   // nodes per range (even); RS/2 u32 words = 25088B/table
constexpr int NSL = 32;      // edge slices
constexpr int NR  = 4;       // ranges (RS*NR >= N)

typedef __attribute__((ext_vector_type(8))) short short8v;   // 8 x bf16
typedef __attribute__((ext_vector_type(4))) float f32x4;

__device__ __forceinline__ unsigned short f2bf(float f) {    // RNE f32->bf16
    unsigned u = __builtin_bit_cast(unsigned, f);
    u += 0x7fffu + ((u >> 16) & 1u);
    return (unsigned short)(u >> 16);
}
__device__ __forceinline__ float bf2f(unsigned s) {
    return __builtin_bit_cast(float, s << 16);
}

// ---- fused per-(range,slice) LDS histograms of row & col, u16-packed ----
// XCD-swizzled decode: r = bid&3 -> all blocks of range r on XCDs {r, r+4}.
__global__ __launch_bounds__(256) void k_hist2(const int* __restrict__ row,
                                               const int* __restrict__ col, int E,
                                               unsigned* __restrict__ deg_t,
                                               unsigned* __restrict__ cnt_t) {
    __shared__ unsigned hd[RS / 2], hc[RS / 2];   // 2 x 25088B
    int bid = blockIdx.x;
    int r = bid & (NR - 1), s = bid >> 2;
    int base = r * RS;
    for (int j = threadIdx.x; j < RS / 2; j += 256) { hd[j] = 0; hc[j] = 0; }
    __syncthreads();
    int ES = (E + NSL - 1) / NSL;
    int lo = s * ES, hi = min(E, lo + ES);
    for (int i = lo + threadIdx.x; i < hi; i += 256) {
        int kr = row[i] - base;
        if ((unsigned)kr < (unsigned)RS) atomicAdd(&hd[kr >> 1], 1u << ((kr & 1) * 16));
        int kc = col[i] - base;
        if ((unsigned)kc < (unsigned)RS) atomicAdd(&hc[kc >> 1], 1u << ((kc & 1) * 16));
    }
    __syncthreads();
    unsigned* td = deg_t + (size_t)(r * NSL + s) * (RS / 2);
    unsigned* tc = cnt_t + (size_t)(r * NSL + s) * (RS / 2);
    for (int j = threadIdx.x; j < RS / 2; j += 256) { td[j] = hd[j]; tc[j] = hc[j]; }
}

// ---- fold slices (1 thread = 1 word = 2 nodes, packed u32 arithmetic):
// dn, in-place exclusive slice-prefix of cnt_t, per-node totals, block partials ----
__global__ __launch_bounds__(128) void k_red2(const unsigned* __restrict__ deg_t,
                                              unsigned* __restrict__ cnt_t,
                                              float* __restrict__ dn, int* __restrict__ cnt,
                                              int* __restrict__ bsum, int N) {
    int t = threadIdx.x;
    int w = blockIdx.x * 128 + t;       // word index; nodes 2w, 2w+1 (same range: RS even)
    int n0 = 2 * w, n1 = n0 + 1;
    int partial = 0;
    if (n0 < N) {
        int r = n0 / RS, ri = n0 - r * RS;
        size_t base = (size_t)(r * NSL) * (RS / 2) + (ri >> 1);
        unsigned d = 0, run = 0;
        #pragma unroll
        for (int s = 0; s < NSL; ++s) d += deg_t[base + (size_t)s * (RS / 2)];
        #pragma unroll
        for (int s = 0; s < NSL; ++s) {
            size_t idx = base + (size_t)s * (RS / 2);
            unsigned c = cnt_t[idx];
            cnt_t[idx] = run;           // packed exclusive prefix
            run += c;
        }
        int d0 = d & 0xffffu, d1 = d >> 16;
        int t0 = run & 0xffffu, t1 = run >> 16;
        dn[n0] = rsqrtf((float)(d0 < 1 ? 1 : d0));
        cnt[n0] = t0;
        partial = t0;
        if (n1 < N) {
            dn[n1] = rsqrtf((float)(d1 < 1 ? 1 : d1));
            cnt[n1] = t1;
            partial += t1;
        }
    }
    __shared__ int sh[128];
    sh[t] = partial;
    __syncthreads();
    #pragma unroll
    for (int d = 64; d; d >>= 1) {
        if (t < d) sh[t] += sh[t + d];
        __syncthreads();
    }
    if (t == 0) bsum[blockIdx.x] = sh[0];
}

__global__ __launch_bounds__(256) void k_scan2(int* __restrict__ bsum, int nb,
                                               int* __restrict__ rowptr, int N, int E) {
    __shared__ int s[256];
    int t = threadIdx.x;
    int v = (t < nb) ? bsum[t] : 0;
    s[t] = v;
    __syncthreads();
    #pragma unroll
    for (int d = 1; d < 256; d <<= 1) {
        int x = (t >= d) ? s[t - d] : 0;
        __syncthreads();
        s[t] += x;
        __syncthreads();
    }
    if (t < nb) bsum[t] = s[t] - v;
    if (t == 0) rowptr[N] = E;
}

__global__ __launch_bounds__(256) void k_scan3(const int* __restrict__ cnt,
                                               const int* __restrict__ bsum,
                                               int* __restrict__ rowptr, int N) {
    __shared__ int s[256];
    int t = threadIdx.x, i = blockIdx.x * 256 + t;
    int v = (i < N) ? cnt[i] : 0;
    s[t] = v;
    __syncthreads();
    #pragma unroll
    for (int d = 1; d < 256; d <<= 1) {
        int x = (t >= d) ? s[t - d] : 0;
        __syncthreads();
        s[t] += x;
        __syncthreads();
    }
    if (i < N) rowptr[i] = bsum[blockIdx.x] + s[t] - v;
}

// ---- fill CSR with LDS cursors; same XCD-swizzled decode as k_hist2 ----
__global__ __launch_bounds__(256) void k_fill2(const int* __restrict__ row,
                                               const int* __restrict__ col,
                                               const unsigned* __restrict__ cnt_t,
                                               const int* __restrict__ rowptr,
                                               int* __restrict__ erow, int E, int N) {
    __shared__ int cur[RS];
    int bid = blockIdx.x;
    int r = bid & (NR - 1), s = bid >> 2;
    int base = r * RS;
    const unsigned* tc = cnt_t + (size_t)(r * NSL + s) * (RS / 2);
    for (int j = threadIdx.x; j < RS; j += 256) {
        int node = base + j;
        int pre = (tc[j >> 1] >> ((j & 1) * 16)) & 0xffffu;
        cur[j] = (node < N) ? (pre + rowptr[node]) : 0;
    }
    __syncthreads();
    int ES = (E + NSL - 1) / NSL;
    int lo = s * ES, hi = min(E, lo + ES);
    for (int i = lo + threadIdx.x; i < hi; i += 256) {
        int c = col[i] - base;
        if ((unsigned)c < (unsigned)RS) {
            int p = atomicAdd(&cur[c], 1);
            erow[p] = row[i];
        }
    }
}

// ---- W_in -> B-fragment-packed bf16 ----
__global__ void k_wprep(const float* __restrict__ W, unsigned short* __restrict__ Wb) {
    int tid = blockIdx.x * 256 + threadIdx.x;          // 2048 threads
    int c = tid >> 8, ks = (tid >> 6) & 3, l = tid & 63;
    int colw  = c * 16 + (l & 15);
    int kbase = ks * 32 + (l >> 4) * 8;
    unsigned short tmp[8];
    #pragma unroll
    for (int j = 0; j < 8; ++j) tmp[j] = f2bf(W[(kbase + j) * HD + colw]);
    #pragma unroll
    for (int j = 0; j < 8; ++j) Wb[tid * 8 + j] = tmp[j];
}

// ---- hb0 = bf16(relu(x @ W_in + b_in)) via MFMA + fused layer-0 gate proj ----
__global__ __launch_bounds__(256) void k_gemm_mfma(
        const float* __restrict__ x, const unsigned short* __restrict__ Wb,
        const float* __restrict__ bias,
        const float* __restrict__ Wg0, const float* __restrict__ bg,
        const float* __restrict__ dn,
        unsigned short* __restrict__ hb,
        float2* __restrict__ adn, float* __restrict__ bplus, int N) {
    int wid  = blockIdx.x * 4 + (threadIdx.x >> 6);
    int lane = threadIdx.x & 63;
    int r0 = wid * 16;
    int lr = lane & 15, lg = lane >> 4;
    int rload = r0 + lr; if (rload > N - 1) rload = N - 1;
    f32x4 acc[8];
    #pragma unroll
    for (int c = 0; c < 8; ++c) acc[c] = (f32x4){0.f, 0.f, 0.f, 0.f};
    #pragma unroll
    for (int ks = 0; ks < 4; ++ks) {
        const float4* xr = (const float4*)(x + (size_t)rload * HD + ks * 32 + lg * 8);
        float4 f0 = xr[0], f1 = xr[1];
        short8v a;
        a[0] = (short)f2bf(f0.x); a[1] = (short)f2bf(f0.y);
        a[2] = (short)f2bf(f0.z); a[3] = (short)f2bf(f0.w);
        a[4] = (short)f2bf(f1.x); a[5] = (short)f2bf(f1.y);
        a[6] = (short)f2bf(f1.z); a[7] = (short)f2bf(f1.w);
        #pragma unroll
        for (int c = 0; c < 8; ++c) {
            short8v b = *(const short8v*)(Wb + ((c * 4 + ks) * 64 + lane) * 8);
            acc[c] = __builtin_amdgcn_mfma_f32_16x16x32_bf16(a, b, acc[c], 0, 0, 0);
        }
    }
    float pa[4] = {0.f, 0.f, 0.f, 0.f}, pb[4] = {0.f, 0.f, 0.f, 0.f};
    #pragma unroll
    for (int c = 0; c < 8; ++c) {
        int colw = c * 16 + lr;
        float bv = bias[colw];
        float w1 = Wg0[colw], w2 = Wg0[HD + colw];
        #pragma unroll
        for (int i = 0; i < 4; ++i) {
            int r = r0 + lg * 4 + i;
            float v = acc[c][i] + bv;
            v = v > 0.0f ? v : 0.0f;
            if (r < N) hb[(size_t)r * HD + colw] = f2bf(v);
            pa[i] += v * w1;
            pb[i] += v * w2;
        }
    }
    #pragma unroll
    for (int mask = 1; mask <= 8; mask <<= 1) {
        #pragma unroll
        for (int i = 0; i < 4; ++i) {
            pa[i] += __shfl_xor(pa[i], mask);
            pb[i] += __shfl_xor(pb[i], mask);
        }
    }
    if (lr == 0) {
        float bg0 = bg[0];
        #pragma unroll
        for (int i = 0; i < 4; ++i) {
            int r = r0 + lg * 4 + i;
            if (r < N) {
                adn[r]   = make_float2(pa[i], dn[r]);
                bplus[r] = pb[i] + bg0;
            }
        }
    }
}

// ---- aggregate + residual(bf16 hb0) + fused next-layer gate projections ----
// quarter-wave: 4 edges in flight; 16 lanes x uint4 (8 bf16) per edge.
__global__ __launch_bounds__(256) void k_agg(
        const int* __restrict__ rowptr, const int* __restrict__ erow,
        const float2* __restrict__ adn, const float* __restrict__ bplus,
        const float* __restrict__ dn,
        const unsigned short* __restrict__ hb_in, const unsigned short* __restrict__ hb0,
        unsigned short* __restrict__ hb_out,
        const float* __restrict__ wg_next, const float* __restrict__ bg, int next_layer,
        float2* __restrict__ adn_out, float* __restrict__ bplus_out, int N) {
    int v = (int)((blockIdx.x * (size_t)blockDim.x + threadIdx.x) >> 6);
    if (v >= N) return;
    int lane = threadIdx.x & 63;
    int ql = lane & 15, q = lane >> 4;
    int beg = rowptr[v], end = rowptr[v + 1];
    float bv = bplus[v];
    float acc[8] = {0.f, 0.f, 0.f, 0.f, 0.f, 0.f, 0.f, 0.f};
    for (int s0 = beg; s0 < end; s0 += 64) {
        int m = end - s0; if (m > 64) m = 64;
        int r_l = 0; float nrm_l = 0.0f;
        if (lane < m) {
            r_l = erow[s0 + lane];
            float2 ad = adn[r_l];
            nrm_l = tanhf(ad.x + bv) * ad.y;     // dn[v] factored out
        }
        int it = (m + 3) >> 2;
        for (int j = 0; j < it; ++j) {
            int src = 4 * j + q;
            int   rr = __shfl(r_l, src);
            float nv = __shfl(nrm_l, src);
            if (src < m) {
                uint4 u = *(const uint4*)(hb_in + (size_t)rr * HD + ql * 8);
                acc[0] += nv * bf2f(u.x & 0xffffu); acc[1] += nv * bf2f(u.x >> 16);
                acc[2] += nv * bf2f(u.y & 0xffffu); acc[3] += nv * bf2f(u.y >> 16);
                acc[4] += nv * bf2f(u.z & 0xffffu); acc[5] += nv * bf2f(u.z >> 16);
                acc[6] += nv * bf2f(u.w & 0xffffu); acc[7] += nv * bf2f(u.w >> 16);
            }
        }
    }
    #pragma unroll
    for (int k = 0; k < 8; ++k) {
        acc[k] += __shfl_xor(acc[k], 16);
        acc[k] += __shfl_xor(acc[k], 32);
    }
    float dnv = dn[v];
    uint4 u0 = *(const uint4*)(hb0 + (size_t)v * HD + ql * 8);
    float o[8];
    o[0] = EPS_RES * bf2f(u0.x & 0xffffu) + dnv * acc[0];
    o[1] = EPS_RES * bf2f(u0.x >> 16)     + dnv * acc[1];
    o[2] = EPS_RES * bf2f(u0.y & 0xffffu) + dnv * acc[2];
    o[3] = EPS_RES * bf2f(u0.y >> 16)     + dnv * acc[3];
    o[4] = EPS_RES * bf2f(u0.z & 0xffffu) + dnv * acc[4];
    o[5] = EPS_RES * bf2f(u0.z >> 16)     + dnv * acc[5];
    o[6] = EPS_RES * bf2f(u0.w & 0xffffu) + dnv * acc[6];
    o[7] = EPS_RES * bf2f(u0.w >> 16)     + dnv * acc[7];
    if (q == 0) {
        uint4 up;
        up.x = (unsigned)f2bf(o[0]) | ((unsigned)f2bf(o[1]) << 16);
        up.y = (unsigned)f2bf(o[2]) | ((unsigned)f2bf(o[3]) << 16);
        up.z = (unsigned)f2bf(o[4]) | ((unsigned)f2bf(o[5]) << 16);
        up.w = (unsigned)f2bf(o[6]) | ((unsigned)f2bf(o[7]) << 16);
        *(uint4*)(hb_out + (size_t)v * HD + ql * 8) = up;
    }
    if (wg_next != nullptr) {
        float4 w1a = *(const float4*)(wg_next + ql * 8);
        float4 w1b = *(const float4*)(wg_next + ql * 8 + 4);
        float4 w2a = *(const float4*)(wg_next + HD + ql * 8);
        float4 w2b = *(const float4*)(wg_next + HD + ql * 8 + 4);
        float pa = o[0]*w1a.x + o[1]*w1a.y + o[2]*w1a.z + o[3]*w1a.w
                 + o[4]*w1b.x + o[5]*w1b.y + o[6]*w1b.z + o[7]*w1b.w;
        float pb = o[0]*w2a.x + o[1]*w2a.y + o[2]*w2a.z + o[3]*w2a.w
                 + o[4]*w2b.x + o[5]*w2b.y + o[6]*w2b.z + o[7]*w2b.w;
        #pragma unroll
        for (int m = 8; m; m >>= 1) {
            pa += __shfl_xor(pa, m);
            pb += __shfl_xor(pb, m);
        }
        if (lane == 0) {
            adn_out[v]   = make_float2(pa, dnv);
            bplus_out[v] = pb + bg[next_layer];
        }
    }
}

// ---- out = log_softmax(h @ W_out + b_out); 16 threads/node, bf16 h ----
__global__ __launch_bounds__(256) void k_out(
        const unsigned short* __restrict__ hb, const float* __restrict__ W,
        const float* __restrict__ bias, float* __restrict__ out, int N) {
    __shared__ float Ws[HD * OD];
    __shared__ unsigned hsu[16 * 64];
    int t = threadIdx.x;
    for (int i = t; i < HD * OD; i += 256) Ws[i] = W[i];
    int n0 = blockIdx.x * 16;
    for (int i = t; i < 16 * 64; i += 256) {
        int node = n0 + (i >> 6);
        hsu[i] = (node < N) ? *(const unsigned*)(hb + (size_t)node * HD + (i & 63) * 2) : 0u;
    }
    __syncthreads();
    int n = n0 + (t >> 4);
    int j = t & 15;
    if (n < N) {
        const unsigned* hrow = &hsu[(t >> 4) * 64];
        float acc = bias[j];
        #pragma unroll 8
        for (int p = 0; p < 64; ++p) {
            unsigned u = hrow[p];
            acc += bf2f(u & 0xffffu) * Ws[(2 * p) * OD + j]
                 + bf2f(u >> 16)     * Ws[(2 * p + 1) * OD + j];
        }
        float m = acc;
        #pragma unroll
        for (int msk = 8; msk; msk >>= 1) m = fmaxf(m, __shfl_xor(m, msk, 16));
        float ex = expf(acc - m);
        float s = ex;
        #pragma unroll
        for (int msk = 8; msk; msk >>= 1) s += __shfl_xor(s, msk, 16);
        out[n * OD + j] = acc - m - logf(s);
    }
}

extern "C" void kernel_launch(void* const* d_in, const int* in_sizes, int n_in,
                              void* d_out, int out_size, void* d_ws, size_t ws_size,
                              hipStream_t stream) {
    const float* x     = (const float*)d_in[0];
    const int*   ei    = (const int*)  d_in[1];
    const float* W_in  = (const float*)d_in[2];
    const float* b_in  = (const float*)d_in[3];
    const float* Wg    = (const float*)d_in[4];
    const float* bg    = (const float*)d_in[5];
    const float* W_out = (const float*)d_in[6];
    const float* b_out = (const float*)d_in[7];
    float* out = (float*)d_out;

    const int N = in_sizes[0] / HD;
    const int E = in_sizes[1] / 2;
    const int L = in_sizes[5];
    const int* row = ei;
    const int* col = ei + E;

    const int tiles   = (N + 15) / 16;
    const int gblocks = (tiles + 3) / 4;
    const int nb      = (N + 255) / 256;          // 196 <= 256 (also k_red2 grid)

    // ---- workspace bump allocator (256B aligned) ----
    char* ws = (char*)d_ws;
    size_t off = 0;
    auto alloc = [&](size_t bytes) -> void* {
        void* p = ws + off;
        off = (off + bytes + 255) & ~(size_t)255;
        return p;
    };
    unsigned*       deg_t  = (unsigned*)      alloc((size_t)NR * NSL * (RS / 2) * 4); // 3.2MB
    unsigned*       cnt_t  = (unsigned*)      alloc((size_t)NR * NSL * (RS / 2) * 4); // 3.2MB
    float*          dn     = (float*)         alloc((size_t)N * 4);
    int*            cnt    = (int*)           alloc((size_t)N * 4);
    float2*         adnA   = (float2*)        alloc((size_t)N * 8);
    float2*         adnB   = (float2*)        alloc((size_t)N * 8);
    float*          bplusA = (float*)         alloc((size_t)N * 4);
    float*          bplusB = (float*)         alloc((size_t)N * 4);
    int*            bsum   = (int*)           alloc((size_t)nb * 4);
    int*            rowptr = (int*)           alloc(((size_t)N + 1) * 4);
    int*            erow   = (int*)           alloc((size_t)E * 4);
    unsigned short* Wb     = (unsigned short*)alloc((size_t)HD * HD * 2);
    unsigned short* hb0    = (unsigned short*)alloc((size_t)N * HD * 2);
    unsigned short* hb1    = (unsigned short*)alloc((size_t)N * HD * 2);
    unsigned short* hb2    = (unsigned short*)alloc((size_t)N * HD * 2);
    (void)ws_size;

    // CSR build (atomic-free at global level)
    k_hist2<<<NR * NSL, 256, 0, stream>>>(row, col, E, deg_t, cnt_t);
    k_red2 <<<nb, 128, 0, stream>>>(deg_t, cnt_t, dn, cnt, bsum, N);
    k_scan2<<<1, 256, 0, stream>>>(bsum, nb, rowptr, N, E);
    k_scan3<<<nb, 256, 0, stream>>>(cnt, bsum, rowptr, N);
    k_fill2<<<NR * NSL, 256, 0, stream>>>(row, col, cnt_t, rowptr, erow, E, N);

    k_wprep<<<8, 256, 0, stream>>>(W_in, Wb);
    k_gemm_mfma<<<gblocks, 256, 0, stream>>>(x, Wb, b_in, Wg, bg, dn,
                                             hb0, adnA, bplusA, N);

    unsigned short* hcur = hb0;
    unsigned short* houts[2] = { hb1, hb2 };
    float2* adns[2]  = { adnA, adnB };
    float*  bpls[2]  = { bplusA, bplusB };
    for (int i = 0; i < L; ++i) {
        const float* wg_next = (i + 1 < L) ? (Wg + (i + 1) * 2 * HD) : nullptr;
        k_agg<<<(N + 3) / 4, 256, 0, stream>>>(
            rowptr, erow, adns[i & 1], bpls[i & 1], dn,
            hcur, hb0, houts[i & 1],
            wg_next, bg, i + 1, adns[(i + 1) & 1], bpls[(i + 1) & 1], N);
        hcur = houts[i & 1];
    }

    k_out<<<(N + 15) / 16, 256, 0, stream>>>(hcur, W_out, b_out, out, N);
}

// Round 13
// 237.780 us; speedup vs baseline: 1.4383x; 1.3565x over previous
//
#include <hip/hip_runtime.h>
#include <hip/hip_bf16.h>
#include <math.h>

// FAGCN: N=50000, E=800000, H=128, OUT=16, L=2
// Round 11 -> 12: k_hist2 was 80us @ 5% occupancy (128 blocks, 98 dependent-load
// iters). Fix: NSL=128 fine slices (512 blocks, ~2/CU), 4-edge ILP via aligned
// int4 loads (98 -> 6 iters), per-kernel XCD decode (hist slice-major for read
// sharing, fill range-major for write merge). Tables streamed, no atomics/memset.

#define EPS_RES 0.3f
constexpr int HD = 128;
constexpr int OD = 16;
constexpr int RS  = 12544;   // nodes per range (even); RS/2 u32 words per table cell
constexpr int NSL = 128;     // fine edge slices (log2 = 7)
constexpr int NR  = 4;       // ranges (RS*NR >= N)

typedef __attribute__((ext_vector_type(8))) short short8v;   // 8 x bf16
typedef __attribute__((ext_vector_type(4))) float f32x4;

__device__ __forceinline__ unsigned short f2bf(float f) {    // RNE f32->bf16
    unsigned u = __builtin_bit_cast(unsigned, f);
    u += 0x7fffu + ((u >> 16) & 1u);
    return (unsigned short)(u >> 16);
}
__device__ __forceinline__ float bf2f(unsigned s) {
    return __builtin_bit_cast(float, s << 16);
}

__device__ __forceinline__ void hadd(unsigned* h, int k) {
    if ((unsigned)k < (unsigned)RS) atomicAdd(&h[k >> 1], 1u << ((k & 1) * 16));
}

// ---- fused per-(range,slice) LDS histograms of row & col, u16-packed ----
// slice-major decode: s=bid&127 -> the 4 range-blocks of one slice sit on the
// SAME XCD (512/8: bid, bid+128.. all == bid mod 8) -> slice fetched once/XCD.
__global__ __launch_bounds__(256) void k_hist(const int* __restrict__ row,
                                              const int* __restrict__ col, int E,
                                              unsigned* __restrict__ deg_t,
                                              unsigned* __restrict__ cnt_t) {
    __shared__ unsigned hd[RS / 2], hc[RS / 2];   // 2 x 25088B
    int bid = blockIdx.x;
    int s = bid & (NSL - 1), r = bid >> 7;
    int base = r * RS;
    for (int j = threadIdx.x; j < RS / 2; j += 256) { hd[j] = 0; hc[j] = 0; }
    __syncthreads();
    int ES = (((E + NSL - 1) / NSL) + 3) & ~3;    // 4-aligned slice size
    int lo = s * ES;
    int n = min(E, lo + ES) - lo; if (n < 0) n = 0;
    int nf = n & ~3;
    for (int i = lo + threadIdx.x * 4; i < lo + nf; i += 1024) {
        int4 rr = *(const int4*)(row + i);
        int4 cc = *(const int4*)(col + i);
        hadd(hd, rr.x - base); hadd(hd, rr.y - base);
        hadd(hd, rr.z - base); hadd(hd, rr.w - base);
        hadd(hc, cc.x - base); hadd(hc, cc.y - base);
        hadd(hc, cc.z - base); hadd(hc, cc.w - base);
    }
    if (threadIdx.x < n - nf) {
        int i = lo + nf + threadIdx.x;
        hadd(hd, row[i] - base);
        hadd(hc, col[i] - base);
    }
    __syncthreads();
    unsigned* td = deg_t + (size_t)(r * NSL + s) * (RS / 2);
    unsigned* tc = cnt_t + (size_t)(r * NSL + s) * (RS / 2);
    for (int j = threadIdx.x; j < RS / 2; j += 256) { td[j] = hd[j]; tc[j] = hc[j]; }
}

// ---- fold slices (1 thread = 1 word = 2 nodes, packed u32 arithmetic):
// dn, in-place exclusive slice-prefix of cnt_t, per-node totals, block partials ----
__global__ __launch_bounds__(128) void k_red2(const unsigned* __restrict__ deg_t,
                                              unsigned* __restrict__ cnt_t,
                                              float* __restrict__ dn, int* __restrict__ cnt,
                                              int* __restrict__ bsum, int N) {
    int t = threadIdx.x;
    int w = blockIdx.x * 128 + t;       // word index; nodes 2w, 2w+1 (same range: RS even)
    int n0 = 2 * w, n1 = n0 + 1;
    int partial = 0;
    if (n0 < N) {
        int r = n0 / RS, ri = n0 - r * RS;
        size_t base = (size_t)(r * NSL) * (RS / 2) + (ri >> 1);
        unsigned d = 0, run = 0;
        for (int s = 0; s < NSL; ++s) d += deg_t[base + (size_t)s * (RS / 2)];
        for (int s = 0; s < NSL; ++s) {
            size_t idx = base + (size_t)s * (RS / 2);
            unsigned c = cnt_t[idx];
            cnt_t[idx] = run;           // packed exclusive prefix
            run += c;
        }
        int d0 = d & 0xffffu, d1 = d >> 16;
        int t0 = run & 0xffffu, t1 = run >> 16;
        dn[n0] = rsqrtf((float)(d0 < 1 ? 1 : d0));
        cnt[n0] = t0;
        partial = t0;
        if (n1 < N) {
            dn[n1] = rsqrtf((float)(d1 < 1 ? 1 : d1));
            cnt[n1] = t1;
            partial += t1;
        }
    }
    __shared__ int sh[128];
    sh[t] = partial;
    __syncthreads();
    #pragma unroll
    for (int d = 64; d; d >>= 1) {
        if (t < d) sh[t] += sh[t + d];
        __syncthreads();
    }
    if (t == 0) bsum[blockIdx.x] = sh[0];
}

__global__ __launch_bounds__(256) void k_scan2(int* __restrict__ bsum, int nb,
                                               int* __restrict__ rowptr, int N, int E) {
    __shared__ int s[256];
    int t = threadIdx.x;
    int v = (t < nb) ? bsum[t] : 0;
    s[t] = v;
    __syncthreads();
    #pragma unroll
    for (int d = 1; d < 256; d <<= 1) {
        int x = (t >= d) ? s[t - d] : 0;
        __syncthreads();
        s[t] += x;
        __syncthreads();
    }
    if (t < nb) bsum[t] = s[t] - v;
    if (t == 0) rowptr[N] = E;
}

__global__ __launch_bounds__(256) void k_scan3(const int* __restrict__ cnt,
                                               const int* __restrict__ bsum,
                                               int* __restrict__ rowptr, int N) {
    __shared__ int s[256];
    int t = threadIdx.x, i = blockIdx.x * 256 + t;
    int v = (i < N) ? cnt[i] : 0;
    s[t] = v;
    __syncthreads();
    #pragma unroll
    for (int d = 1; d < 256; d <<= 1) {
        int x = (t >= d) ? s[t - d] : 0;
        __syncthreads();
        s[t] += x;
        __syncthreads();
    }
    if (i < N) rowptr[i] = bsum[blockIdx.x] + s[t] - v;
}

// ---- fill CSR with LDS cursors; range-major decode (r=bid&3): all blocks of
// range r on XCDs {r, r+4} -> erow partial-line writes merge in L2. ----
__global__ __launch_bounds__(256) void k_fill2(const int* __restrict__ row,
                                               const int* __restrict__ col,
                                               const unsigned* __restrict__ cnt_t,
                                               const int* __restrict__ rowptr,
                                               int* __restrict__ erow, int E, int N) {
    __shared__ int cur[RS];
    int bid = blockIdx.x;
    int r = bid & (NR - 1), s = bid >> 2;
    int base = r * RS;
    const unsigned* tc = cnt_t + (size_t)(r * NSL + s) * (RS / 2);
    for (int j = threadIdx.x; j < RS; j += 256) {
        int node = base + j;
        int pre = (tc[j >> 1] >> ((j & 1) * 16)) & 0xffffu;
        cur[j] = (node < N) ? (pre + rowptr[node]) : 0;
    }
    __syncthreads();
    int ES = (((E + NSL - 1) / NSL) + 3) & ~3;
    int lo = s * ES;
    int n = min(E, lo + ES) - lo; if (n < 0) n = 0;
    int nf = n & ~3;
    for (int i = lo + threadIdx.x * 4; i < lo + nf; i += 1024) {
        int4 cc = *(const int4*)(col + i);
        int4 rr = *(const int4*)(row + i);
        int c;
        c = cc.x - base; if ((unsigned)c < (unsigned)RS) { int p = atomicAdd(&cur[c], 1); erow[p] = rr.x; }
        c = cc.y - base; if ((unsigned)c < (unsigned)RS) { int p = atomicAdd(&cur[c], 1); erow[p] = rr.y; }
        c = cc.z - base; if ((unsigned)c < (unsigned)RS) { int p = atomicAdd(&cur[c], 1); erow[p] = rr.z; }
        c = cc.w - base; if ((unsigned)c < (unsigned)RS) { int p = atomicAdd(&cur[c], 1); erow[p] = rr.w; }
    }
    if (threadIdx.x < n - nf) {
        int i = lo + nf + threadIdx.x;
        int c = col[i] - base;
        if ((unsigned)c < (unsigned)RS) { int p = atomicAdd(&cur[c], 1); erow[p] = row[i]; }
    }
}

// ---- W_in -> B-fragment-packed bf16 ----
__global__ void k_wprep(const float* __restrict__ W, unsigned short* __restrict__ Wb) {
    int tid = blockIdx.x * 256 + threadIdx.x;          // 2048 threads
    int c = tid >> 8, ks = (tid >> 6) & 3, l = tid & 63;
    int colw  = c * 16 + (l & 15);
    int kbase = ks * 32 + (l >> 4) * 8;
    unsigned short tmp[8];
    #pragma unroll
    for (int j = 0; j < 8; ++j) tmp[j] = f2bf(W[(kbase + j) * HD + colw]);
    #pragma unroll
    for (int j = 0; j < 8; ++j) Wb[tid * 8 + j] = tmp[j];
}

// ---- hb0 = bf16(relu(x @ W_in + b_in)) via MFMA + fused layer-0 gate proj ----
__global__ __launch_bounds__(256) void k_gemm_mfma(
        const float* __restrict__ x, const unsigned short* __restrict__ Wb,
        const float* __restrict__ bias,
        const float* __restrict__ Wg0, const float* __restrict__ bg,
        const float* __restrict__ dn,
        unsigned short* __restrict__ hb,
        float2* __restrict__ adn, float* __restrict__ bplus, int N) {
    int wid  = blockIdx.x * 4 + (threadIdx.x >> 6);
    int lane = threadIdx.x & 63;
    int r0 = wid * 16;
    int lr = lane & 15, lg = lane >> 4;
    int rload = r0 + lr; if (rload > N - 1) rload = N - 1;
    f32x4 acc[8];
    #pragma unroll
    for (int c = 0; c < 8; ++c) acc[c] = (f32x4){0.f, 0.f, 0.f, 0.f};
    #pragma unroll
    for (int ks = 0; ks < 4; ++ks) {
        const float4* xr = (const float4*)(x + (size_t)rload * HD + ks * 32 + lg * 8);
        float4 f0 = xr[0], f1 = xr[1];
        short8v a;
        a[0] = (short)f2bf(f0.x); a[1] = (short)f2bf(f0.y);
        a[2] = (short)f2bf(f0.z); a[3] = (short)f2bf(f0.w);
        a[4] = (short)f2bf(f1.x); a[5] = (short)f2bf(f1.y);
        a[6] = (short)f2bf(f1.z); a[7] = (short)f2bf(f1.w);
        #pragma unroll
        for (int c = 0; c < 8; ++c) {
            short8v b = *(const short8v*)(Wb + ((c * 4 + ks) * 64 + lane) * 8);
            acc[c] = __builtin_amdgcn_mfma_f32_16x16x32_bf16(a, b, acc[c], 0, 0, 0);
        }
    }
    float pa[4] = {0.f, 0.f, 0.f, 0.f}, pb[4] = {0.f, 0.f, 0.f, 0.f};
    #pragma unroll
    for (int c = 0; c < 8; ++c) {
        int colw = c * 16 + lr;
        float bv = bias[colw];
        float w1 = Wg0[colw], w2 = Wg0[HD + colw];
        #pragma unroll
        for (int i = 0; i < 4; ++i) {
            int r = r0 + lg * 4 + i;
            float v = acc[c][i] + bv;
            v = v > 0.0f ? v : 0.0f;
            if (r < N) hb[(size_t)r * HD + colw] = f2bf(v);
            pa[i] += v * w1;
            pb[i] += v * w2;
        }
    }
    #pragma unroll
    for (int mask = 1; mask <= 8; mask <<= 1) {
        #pragma unroll
        for (int i = 0; i < 4; ++i) {
            pa[i] += __shfl_xor(pa[i], mask);
            pb[i] += __shfl_xor(pb[i], mask);
        }
    }
    if (lr == 0) {
        float bg0 = bg[0];
        #pragma unroll
        for (int i = 0; i < 4; ++i) {
            int r = r0 + lg * 4 + i;
            if (r < N) {
                adn[r]   = make_float2(pa[i], dn[r]);
                bplus[r] = pb[i] + bg0;
            }
        }
    }
}

// ---- aggregate + residual(bf16 hb0) + fused next-layer gate projections ----
// quarter-wave: 4 edges in flight; 16 lanes x uint4 (8 bf16) per edge.
__global__ __launch_bounds__(256) void k_agg(
        const int* __restrict__ rowptr, const int* __restrict__ erow,
        const float2* __restrict__ adn, const float* __restrict__ bplus,
        const float* __restrict__ dn,
        const unsigned short* __restrict__ hb_in, const unsigned short* __restrict__ hb0,
        unsigned short* __restrict__ hb_out,
        const float* __restrict__ wg_next, const float* __restrict__ bg, int next_layer,
        float2* __restrict__ adn_out, float* __restrict__ bplus_out, int N) {
    int v = (int)((blockIdx.x * (size_t)blockDim.x + threadIdx.x) >> 6);
    if (v >= N) return;
    int lane = threadIdx.x & 63;
    int ql = lane & 15, q = lane >> 4;
    int beg = rowptr[v], end = rowptr[v + 1];
    float bv = bplus[v];
    float acc[8] = {0.f, 0.f, 0.f, 0.f, 0.f, 0.f, 0.f, 0.f};
    for (int s0 = beg; s0 < end; s0 += 64) {
        int m = end - s0; if (m > 64) m = 64;
        int r_l = 0; float nrm_l = 0.0f;
        if (lane < m) {
            r_l = erow[s0 + lane];
            float2 ad = adn[r_l];
            nrm_l = tanhf(ad.x + bv) * ad.y;     // dn[v] factored out
        }
        int it = (m + 3) >> 2;
        for (int j = 0; j < it; ++j) {
            int src = 4 * j + q;
            int   rr = __shfl(r_l, src);
            float nv = __shfl(nrm_l, src);
            if (src < m) {
                uint4 u = *(const uint4*)(hb_in + (size_t)rr * HD + ql * 8);
                acc[0] += nv * bf2f(u.x & 0xffffu); acc[1] += nv * bf2f(u.x >> 16);
                acc[2] += nv * bf2f(u.y & 0xffffu); acc[3] += nv * bf2f(u.y >> 16);
                acc[4] += nv * bf2f(u.z & 0xffffu); acc[5] += nv * bf2f(u.z >> 16);
                acc[6] += nv * bf2f(u.w & 0xffffu); acc[7] += nv * bf2f(u.w >> 16);
            }
        }
    }
    #pragma unroll
    for (int k = 0; k < 8; ++k) {
        acc[k] += __shfl_xor(acc[k], 16);
        acc[k] += __shfl_xor(acc[k], 32);
    }
    float dnv = dn[v];
    uint4 u0 = *(const uint4*)(hb0 + (size_t)v * HD + ql * 8);
    float o[8];
    o[0] = EPS_RES * bf2f(u0.x & 0xffffu) + dnv * acc[0];
    o[1] = EPS_RES * bf2f(u0.x >> 16)     + dnv * acc[1];
    o[2] = EPS_RES * bf2f(u0.y & 0xffffu) + dnv * acc[2];
    o[3] = EPS_RES * bf2f(u0.y >> 16)     + dnv * acc[3];
    o[4] = EPS_RES * bf2f(u0.z & 0xffffu) + dnv * acc[4];
    o[5] = EPS_RES * bf2f(u0.z >> 16)     + dnv * acc[5];
    o[6] = EPS_RES * bf2f(u0.w & 0xffffu) + dnv * acc[6];
    o[7] = EPS_RES * bf2f(u0.w >> 16)     + dnv * acc[7];
    if (q == 0) {
        uint4 up;
        up.x = (unsigned)f2bf(o[0]) | ((unsigned)f2bf(o[1]) << 16);
        up.y = (unsigned)f2bf(o[2]) | ((unsigned)f2bf(o[3]) << 16);
        up.z = (unsigned)f2bf(o[4]) | ((unsigned)f2bf(o[5]) << 16);
        up.w = (unsigned)f2bf(o[6]) | ((unsigned)f2bf(o[7]) << 16);
        *(uint4*)(hb_out + (size_t)v * HD + ql * 8) = up;
    }
    if (wg_next != nullptr) {
        float4 w1a = *(const float4*)(wg_next + ql * 8);
        float4 w1b = *(const float4*)(wg_next + ql * 8 + 4);
        float4 w2a = *(const float4*)(wg_next + HD + ql * 8);
        float4 w2b = *(const float4*)(wg_next + HD + ql * 8 + 4);
        float pa = o[0]*w1a.x + o[1]*w1a.y + o[2]*w1a.z + o[3]*w1a.w
                 + o[4]*w1b.x + o[5]*w1b.y + o[6]*w1b.z + o[7]*w1b.w;
        float pb = o[0]*w2a.x + o[1]*w2a.y + o[2]*w2a.z + o[3]*w2a.w
                 + o[4]*w2b.x + o[5]*w2b.y + o[6]*w2b.z + o[7]*w2b.w;
        #pragma unroll
        for (int m = 8; m; m >>= 1) {
            pa += __shfl_xor(pa, m);
            pb += __shfl_xor(pb, m);
        }
        if (lane == 0) {
            adn_out[v]   = make_float2(pa, dnv);
            bplus_out[v] = pb + bg[next_layer];
        }
    }
}

// ---- out = log_softmax(h @ W_out + b_out); 16 threads/node, bf16 h ----
__global__ __launch_bounds__(256) void k_out(
        const unsigned short* __restrict__ hb, const float* __restrict__ W,
        const float* __restrict__ bias, float* __restrict__ out, int N) {
    __shared__ float Ws[HD * OD];
    __shared__ unsigned hsu[16 * 64];
    int t = threadIdx.x;
    for (int i = t; i < HD * OD; i += 256) Ws[i] = W[i];
    int n0 = blockIdx.x * 16;
    for (int i = t; i < 16 * 64; i += 256) {
        int node = n0 + (i >> 6);
        hsu[i] = (node < N) ? *(const unsigned*)(hb + (size_t)node * HD + (i & 63) * 2) : 0u;
    }
    __syncthreads();
    int n = n0 + (t >> 4);
    int j = t & 15;
    if (n < N) {
        const unsigned* hrow = &hsu[(t >> 4) * 64];
        float acc = bias[j];
        #pragma unroll 8
        for (int p = 0; p < 64; ++p) {
            unsigned u = hrow[p];
            acc += bf2f(u & 0xffffu) * Ws[(2 * p) * OD + j]
                 + bf2f(u >> 16)     * Ws[(2 * p + 1) * OD + j];
        }
        float m = acc;
        #pragma unroll
        for (int msk = 8; msk; msk >>= 1) m = fmaxf(m, __shfl_xor(m, msk, 16));
        float ex = expf(acc - m);
        float s = ex;
        #pragma unroll
        for (int msk = 8; msk; msk >>= 1) s += __shfl_xor(s, msk, 16);
        out[n * OD + j] = acc - m - logf(s);
    }
}

extern "C" void kernel_launch(void* const* d_in, const int* in_sizes, int n_in,
                              void* d_out, int out_size, void* d_ws, size_t ws_size,
                              hipStream_t stream) {
    const float* x     = (const float*)d_in[0];
    const int*   ei    = (const int*)  d_in[1];
    const float* W_in  = (const float*)d_in[2];
    const float* b_in  = (const float*)d_in[3];
    const float* Wg    = (const float*)d_in[4];
    const float* bg    = (const float*)d_in[5];
    const float* W_out = (const float*)d_in[6];
    const float* b_out = (const float*)d_in[7];
    float* out = (float*)d_out;

    const int N = in_sizes[0] / HD;
    const int E = in_sizes[1] / 2;
    const int L = in_sizes[5];
    const int* row = ei;
    const int* col = ei + E;

    const int tiles   = (N + 15) / 16;
    const int gblocks = (tiles + 3) / 4;
    const int nwords  = (N + 1) / 2;
    const int nbred   = (nwords + 127) / 128;     // 196 (block b covers nodes [256b,256b+256))
    const int nb      = (N + 255) / 256;          // 196, same node coverage as nbred

    // ---- workspace bump allocator (256B aligned) ----
    char* ws = (char*)d_ws;
    size_t off = 0;
    auto alloc = [&](size_t bytes) -> void* {
        void* p = ws + off;
        off = (off + bytes + 255) & ~(size_t)255;
        return p;
    };
    unsigned*       deg_t  = (unsigned*)      alloc((size_t)NR * NSL * (RS / 2) * 4); // 12.8MB
    unsigned*       cnt_t  = (unsigned*)      alloc((size_t)NR * NSL * (RS / 2) * 4); // 12.8MB
    float*          dn     = (float*)         alloc((size_t)N * 4);
    int*            cnt    = (int*)           alloc((size_t)N * 4);
    float2*         adnA   = (float2*)        alloc((size_t)N * 8);
    float2*         adnB   = (float2*)        alloc((size_t)N * 8);
    float*          bplusA = (float*)         alloc((size_t)N * 4);
    float*          bplusB = (float*)         alloc((size_t)N * 4);
    int*            bsum   = (int*)           alloc((size_t)nbred * 4);
    int*            rowptr = (int*)           alloc(((size_t)N + 1) * 4);
    int*            erow   = (int*)           alloc((size_t)E * 4);
    unsigned short* Wb     = (unsigned short*)alloc((size_t)HD * HD * 2);
    unsigned short* hb0    = (unsigned short*)alloc((size_t)N * HD * 2);
    unsigned short* hb1    = (unsigned short*)alloc((size_t)N * HD * 2);
    unsigned short* hb2    = (unsigned short*)alloc((size_t)N * HD * 2);
    (void)ws_size;

    // CSR build (atomic-free at global level; no memset needed)
    k_hist <<<NR * NSL, 256, 0, stream>>>(row, col, E, deg_t, cnt_t);
    k_red2 <<<nbred, 128, 0, stream>>>(deg_t, cnt_t, dn, cnt, bsum, N);
    k_scan2<<<1, 256, 0, stream>>>(bsum, nbred, rowptr, N, E);
    k_scan3<<<nb, 256, 0, stream>>>(cnt, bsum, rowptr, N);
    k_fill2<<<NR * NSL, 256, 0, stream>>>(row, col, cnt_t, rowptr, erow, E, N);

    k_wprep<<<8, 256, 0, stream>>>(W_in, Wb);
    k_gemm_mfma<<<gblocks, 256, 0, stream>>>(x, Wb, b_in, Wg, bg, dn,
                                             hb0, adnA, bplusA, N);

    unsigned short* hcur = hb0;
    unsigned short* houts[2] = { hb1, hb2 };
    float2* adns[2]  = { adnA, adnB };
    float*  bpls[2]  = { bplusA, bplusB };
    for (int i = 0; i < L; ++i) {
        const float* wg_next = (i + 1 < L) ? (Wg + (i + 1) * 2 * HD) : nullptr;
        k_agg<<<(N + 3) / 4, 256, 0, stream>>>(
            rowptr, erow, adns[i & 1], bpls[i & 1], dn,
            hcur, hb0, houts[i & 1],
            wg_next, bg, i + 1, adns[(i + 1) & 1], bpls[(i + 1) & 1], N);
        hcur = houts[i & 1];
    }

    k_out<<<(N + 15) / 16, 256, 0, stream>>>(hcur, W_out, b_out, out, N);
}